// Round 3
// baseline (352.775 us; speedup 1.0000x reference)
//
#include <hip/hip_runtime.h>
#include <math.h>

#define BSZ 32
#define CCH 192
#define NPIX 784
#define NP 896          // padded N (896 = 2*448)
#define OUTC 384
#define KNN 9
#define CING 96
#define COUTG 96

typedef short s8v __attribute__((ext_vector_type(8)));
typedef float f4v __attribute__((ext_vector_type(4)));

// ---------------- ws layout ----------------
#define XHI_BYTES ((size_t)BSZ * NP * CCH * 2)      // 11,010,048
#define XLO_BYTES ((size_t)BSZ * NP * CCH * 2)      // 11,010,048
#define SQ_BYTES  ((size_t)BSZ * NP * 4)            //    114,688
#define IDX_BYTES ((size_t)BSZ * NPIX * KNN * 4)    //    903,168
// tbuf: BSZ*192*NPIX*4 = 19,267,584   total ~42.3 MB

__device__ __forceinline__ float gelu_exact(float u) {
    return 0.5f * u * (1.0f + erff(u * 0.70710678118654752440f));
}
__device__ __forceinline__ ushort bf16_rne(float f) {
    uint u = __float_as_uint(f);
    uint r = (u + 0x7fffu + ((u >> 16) & 1u)) >> 16;
    return (ushort)r;
}
__device__ __forceinline__ float bf16f(ushort h) { return __uint_as_float(((uint)h) << 16); }

// ---------------- K1: normalize -> bf16 hi/lo in node-major [b][n][c] + sq ----------------
__global__ __launch_bounds__(256) void k1_normalize(const float* __restrict__ x,
                                                    ushort* __restrict__ xhi,
                                                    ushort* __restrict__ xlo,
                                                    float* __restrict__ sq) {
    __shared__ ushort hs[64][CCH + 4];
    __shared__ ushort ls[64][CCH + 4];
    int b = blockIdx.y;
    int n0 = blockIdx.x * 64;
    int t = threadIdx.x;
    int ln = t >> 2;          // local node 0..63
    int part = t & 3;         // 48 channels each
    int n = n0 + ln;
    const float* xb = x + (size_t)b * CCH * NPIX;

    float ss = 0.f;
    if (n < NPIX) {
        for (int c = part * 48; c < part * 48 + 48; ++c) {
            float v = xb[c * NPIX + n];
            ss = fmaf(v, v, ss);
        }
    }
    ss += __shfl_xor(ss, 1);
    ss += __shfl_xor(ss, 2);
    float inv = 1.0f / fmaxf(sqrtf(ss), 1e-12f);

    float s2 = 0.f;
    for (int c = part * 48; c < part * 48 + 48; ++c) {
        float v = (n < NPIX) ? xb[c * NPIX + n] * inv : 0.f;
        ushort h = bf16_rne(v);
        ushort l = bf16_rne(v - bf16f(h));
        hs[ln][c] = h;
        ls[ln][c] = l;
        s2 = fmaf(v, v, s2);
    }
    s2 += __shfl_xor(s2, 1);
    s2 += __shfl_xor(s2, 2);
    if (part == 0) sq[b * NP + n] = (n < NPIX) ? s2 : 1e30f;

    __syncthreads();
    uint* hdst = (uint*)(xhi + ((size_t)b * NP + n0) * CCH);
    uint* ldst = (uint*)(xlo + ((size_t)b * NP + n0) * CCH);
    for (int i = t; i < 64 * (CCH / 2); i += 256) {
        int row = i / (CCH / 2), col = i - row * (CCH / 2);
        hdst[i] = *(const uint*)((const char*)&hs[row][0] + col * 4);
        ldst[i] = *(const uint*)((const char*)&ls[row][0] + col * 4);
    }
}

// ---------------- K2: barrier-free MFMA knn ----------------
// A-operand = candidates (D rows), B-operand = queries (D cols).
// Wave = (batch, qtile of 32, candidate half of 448). In-register top-9 per
// lane (each lane sees one query col x 4 cand rows per fragment); final 8-list
// merge (2 waves x 4 row-groups) per query via small LDS + one barrier.
__device__ __forceinline__ bool lt_pair(float v, int id, float dv, int di) {
    return (v < dv) || (v == dv && id < di);
}
__device__ __forceinline__ void ins9(float (&d)[KNN], int (&ii)[KNN], float v, int id) {
    if (!lt_pair(v, id, d[KNN - 1], ii[KNN - 1])) return;
    bool cprev = true;
#pragma unroll
    for (int p = KNN - 1; p >= 0; --p) {
        bool cp = (p == 0) ? false : lt_pair(v, id, d[p - 1], ii[p - 1]);
        float nd = cp ? d[p - 1] : (cprev ? v : d[p]);
        int nid = cp ? ii[p - 1] : (cprev ? id : ii[p]);
        d[p] = nd; ii[p] = nid; cprev = cp;
    }
}

__global__ __launch_bounds__(128) void k2_knn(const ushort* __restrict__ xhi,
                                              const ushort* __restrict__ xlo,
                                              const float* __restrict__ sq,
                                              int* __restrict__ nnidx) {
    __shared__ float dls[2][2][64][KNN];
    __shared__ int   ils[2][2][64][KNN];
    int wg = blockIdx.x;                       // 800 blocks = 8 xcd * (4 b * 25 qt)
    int b  = (wg & 7) * 4 + (wg >> 3) / 25;    // batch-per-XCD grouping for L2 reuse
    int qt = (wg >> 3) % 25;
    int t = threadIdx.x, w = t >> 6, l = t & 63;
    int lc = l & 15, lk = l >> 4;
    int q0 = qt * 32;
    const ushort* hb = xhi + (size_t)b * NP * CCH;
    const ushort* lb = xlo + (size_t)b * NP * CCH;

    // resident queries (B-operand): col = lc -> query q0 + qg*16 + lc
    s8v qh[2][6], ql[2][6];
#pragma unroll
    for (int qg = 0; qg < 2; ++qg) {
        const ushort* ph = hb + (size_t)(q0 + qg * 16 + lc) * CCH + lk * 8;
        const ushort* pl = lb + (size_t)(q0 + qg * 16 + lc) * CCH + lk * 8;
#pragma unroll
        for (int kc = 0; kc < 6; ++kc) {
            qh[qg][kc] = *(const s8v*)(ph + kc * 32);
            ql[qg][kc] = *(const s8v*)(pl + kc * 32);
        }
    }

    float d9[2][KNN]; int i9[2][KNN];
#pragma unroll
    for (int qg = 0; qg < 2; ++qg)
#pragma unroll
        for (int r = 0; r < KNN; ++r) { d9[qg][r] = 3.4e38f; i9[qg][r] = 0x7fffffff; }

    const float* sqb = sq + b * NP;
    for (int tt = 0; tt < 14; ++tt) {
        int n0 = w * 448 + tt * 32;
        const ushort* c0h = hb + (size_t)(n0 + lc) * CCH + lk * 8;
        const ushort* c0l = lb + (size_t)(n0 + lc) * CCH + lk * 8;
        const ushort* c1h = c0h + (size_t)16 * CCH;
        const ushort* c1l = c0l + (size_t)16 * CCH;
        f4v aH[2][2], aX[2][2];
#pragma unroll
        for (int cs = 0; cs < 2; ++cs)
#pragma unroll
            for (int qg = 0; qg < 2; ++qg) {
                aH[cs][qg] = (f4v){0.f, 0.f, 0.f, 0.f};
                aX[cs][qg] = (f4v){0.f, 0.f, 0.f, 0.f};
            }
#pragma unroll
        for (int kc = 0; kc < 6; ++kc) {
            s8v v0h = *(const s8v*)(c0h + kc * 32);
            s8v v1h = *(const s8v*)(c1h + kc * 32);
            s8v v0l = *(const s8v*)(c0l + kc * 32);
            s8v v1l = *(const s8v*)(c1l + kc * 32);
            aH[0][0] = __builtin_amdgcn_mfma_f32_16x16x32_bf16(v0h, qh[0][kc], aH[0][0], 0, 0, 0);
            aH[0][1] = __builtin_amdgcn_mfma_f32_16x16x32_bf16(v0h, qh[1][kc], aH[0][1], 0, 0, 0);
            aH[1][0] = __builtin_amdgcn_mfma_f32_16x16x32_bf16(v1h, qh[0][kc], aH[1][0], 0, 0, 0);
            aH[1][1] = __builtin_amdgcn_mfma_f32_16x16x32_bf16(v1h, qh[1][kc], aH[1][1], 0, 0, 0);
            aX[0][0] = __builtin_amdgcn_mfma_f32_16x16x32_bf16(v0l, qh[0][kc], aX[0][0], 0, 0, 0);
            aX[0][0] = __builtin_amdgcn_mfma_f32_16x16x32_bf16(v0h, ql[0][kc], aX[0][0], 0, 0, 0);
            aX[0][1] = __builtin_amdgcn_mfma_f32_16x16x32_bf16(v0l, qh[1][kc], aX[0][1], 0, 0, 0);
            aX[0][1] = __builtin_amdgcn_mfma_f32_16x16x32_bf16(v0h, ql[1][kc], aX[0][1], 0, 0, 0);
            aX[1][0] = __builtin_amdgcn_mfma_f32_16x16x32_bf16(v1l, qh[0][kc], aX[1][0], 0, 0, 0);
            aX[1][0] = __builtin_amdgcn_mfma_f32_16x16x32_bf16(v1h, ql[0][kc], aX[1][0], 0, 0, 0);
            aX[1][1] = __builtin_amdgcn_mfma_f32_16x16x32_bf16(v1l, qh[1][kc], aX[1][1], 0, 0, 0);
            aX[1][1] = __builtin_amdgcn_mfma_f32_16x16x32_bf16(v1h, ql[1][kc], aX[1][1], 0, 0, 0);
        }
        // dist = sq[cand] - 2*dot; cand row = n0 + cs*16 + lk*4 + r, query col = lc
#pragma unroll
        for (int cs = 0; cs < 2; ++cs) {
            f4v sv = *(const f4v*)(sqb + n0 + cs * 16 + lk * 4);
#pragma unroll
            for (int qg = 0; qg < 2; ++qg) {
#pragma unroll
                for (int r = 0; r < 4; ++r) {
                    float dist = fmaf(-2.f, aH[cs][qg][r] + aX[cs][qg][r], sv[r]);
                    ins9(d9[qg], i9[qg], dist, n0 + cs * 16 + lk * 4 + r);
                }
            }
        }
    }

    // dump 8 sorted lists per query (2 waves x 4 lk-groups) and merge
#pragma unroll
    for (int qg = 0; qg < 2; ++qg)
#pragma unroll
        for (int r = 0; r < KNN; ++r) {
            dls[w][qg][l][r] = d9[qg][r];
            ils[w][qg][l][r] = i9[qg][r];
        }
    __syncthreads();
    if (t < 32) {
        int qg = t >> 4, col = t & 15;
        int q = q0 + qg * 16 + col;
        if (q < NPIX) {
            int pk[8] = {0, 0, 0, 0, 0, 0, 0, 0};
            int* op = nnidx + ((size_t)b * NPIX + q) * KNN;
            for (int r = 0; r < KNN; ++r) {
                float best = 3.4e38f; int bi = 0x7fffffff; int bk = 0;
#pragma unroll
                for (int k = 0; k < 8; ++k) {
                    int ww = k >> 2, kk = k & 3;
                    int idx = pk[k] < KNN ? pk[k] : KNN - 1;
                    float v = dls[ww][qg][col + kk * 16][idx];
                    int ii = ils[ww][qg][col + kk * 16][idx];
                    if (pk[k] < KNN && lt_pair(v, ii, best, bi)) { best = v; bi = ii; bk = k; }
                }
                op[r] = bi;
#pragma unroll
                for (int k = 0; k < 8; ++k) pk[k] += (k == bk) ? 1 : 0;
            }
        }
    }
}

// ---------------- K3: t[og,n] = dot96(w[og], x[half,:,n]); fused gelu for groups 0/1 ----------------
#define NT3 128
__global__ __launch_bounds__(256) void k3_proj(const float* __restrict__ x,
                                               const float* __restrict__ w,
                                               const float* __restrict__ bias,
                                               float* __restrict__ out,
                                               float* __restrict__ tbuf) {
    __shared__ float wgT[CING][COUTG + 1];   // [c][og]
    __shared__ float xc[16][NT3];
    int nt = blockIdx.x;     // 0..6
    int g  = blockIdx.y;     // 0..3
    int b  = blockIdx.z;
    int t  = threadIdx.x;
    int n0 = nt * NT3;
    int tog = t >> 4;        // 0..15 : og = tog*6 .. +5
    int tn  = t & 15;        // n = n0 + tn*8 .. +7

    for (int i = t; i < CING * COUTG; i += 256) {
        int og = i / 96, c = i - og * 96;
        wgT[c][og] = w[(g * COUTG + og) * CING + c];
    }

    float acc[6][8];
#pragma unroll
    for (int i = 0; i < 6; ++i)
#pragma unroll
        for (int j = 0; j < 8; ++j) acc[i][j] = 0.f;

    int chalf = (g & 1) * CING;
    for (int cc = 0; cc < CING; cc += 16) {
        __syncthreads();
#pragma unroll
        for (int i = t; i < 16 * NT3; i += 256) {
            int ci = i >> 7, ni = i & 127;
            int gn = n0 + ni;
            xc[ci][ni] = (gn < NPIX) ? x[((size_t)b * CCH + chalf + cc + ci) * NPIX + gn] : 0.f;
        }
        __syncthreads();
#pragma unroll
        for (int ci = 0; ci < 16; ++ci) {
            float wv[6];
#pragma unroll
            for (int i = 0; i < 6; ++i) wv[i] = wgT[cc + ci][tog * 6 + i];
            const float4 xa = *(const float4*)&xc[ci][tn * 8];
            const float4 xb2 = *(const float4*)&xc[ci][tn * 8 + 4];
            float xv[8] = {xa.x, xa.y, xa.z, xa.w, xb2.x, xb2.y, xb2.z, xb2.w};
#pragma unroll
            for (int i = 0; i < 6; ++i)
#pragma unroll
                for (int j = 0; j < 8; ++j)
                    acc[i][j] = fmaf(wv[i], xv[j], acc[i][j]);
        }
    }

#pragma unroll
    for (int i = 0; i < 6; ++i) {
        int og = tog * 6 + i;
        int ogg = g * COUTG + og;
        float bv = bias[ogg];
#pragma unroll
        for (int j = 0; j < 8; ++j) {
            int n = n0 + tn * 8 + j;
            if (n < NPIX) {
                if (g < 2)
                    out[((size_t)b * OUTC + ogg) * NPIX + n] = gelu_exact(acc[i][j] + bv);
                else
                    tbuf[((size_t)b * 192 + (g - 2) * COUTG + og) * NPIX + n] = acc[i][j];
            }
        }
    }
}

// ---------------- K4: groups 2/3  out = max_k gelu(t[idx_k] - t[n] + bias) ----------------
// gelu is unimodal (min at u*~-0.752): max over set = max(gelu(umin), gelu(umax))
__global__ __launch_bounds__(256) void k4_gather(const float* __restrict__ tbuf,
                                                 const int* __restrict__ nnidx,
                                                 const float* __restrict__ bias,
                                                 float* __restrict__ out) {
    __shared__ float trow[NPIX];
    int og2 = blockIdx.x;    // 0..191
    int b = blockIdx.y;
    int t = threadIdx.x;
    const float* tr = tbuf + ((size_t)b * 192 + og2) * NPIX;
    for (int i = t; i < NPIX; i += 256) trow[i] = tr[i];
    __syncthreads();
    float bv = bias[192 + og2];
    for (int n = t; n < NPIX; n += 256) {
        float ti = trow[n];
        const int* ip = nnidx + ((size_t)b * NPIX + n) * KNN;
        float umin = 3.4e38f, umax = -3.4e38f;
#pragma unroll
        for (int k = 0; k < KNN; ++k) {
            int j = ip[k];
            float u = trow[j] - ti + bv;
            umin = fminf(umin, u);
            umax = fmaxf(umax, u);
        }
        float m = fmaxf(gelu_exact(umin), gelu_exact(umax));
        out[((size_t)b * OUTC + 192 + og2) * NPIX + n] = m;
    }
}

extern "C" void kernel_launch(void* const* d_in, const int* in_sizes, int n_in,
                              void* d_out, int out_size, void* d_ws, size_t ws_size,
                              hipStream_t stream) {
    const float* x    = (const float*)d_in[0];
    const float* w    = (const float*)d_in[1];
    const float* bias = (const float*)d_in[2];
    float* out = (float*)d_out;
    char* ws = (char*)d_ws;

    ushort* xhi  = (ushort*)(ws);
    ushort* xlo  = (ushort*)(ws + XHI_BYTES);
    float*  sq   = (float*) (ws + XHI_BYTES + XLO_BYTES);
    int*    nnidx= (int*)   (ws + XHI_BYTES + XLO_BYTES + SQ_BYTES);
    float*  tbuf = (float*) (ws + XHI_BYTES + XLO_BYTES + SQ_BYTES + IDX_BYTES);

    k1_normalize<<<dim3(NP / 64, BSZ), 256, 0, stream>>>(x, xhi, xlo, sq);
    k2_knn<<<dim3(800), 128, 0, stream>>>(xhi, xlo, sq, nnidx);
    k3_proj<<<dim3(7, 4, BSZ), 256, 0, stream>>>(x, w, bias, out, tbuf);
    k4_gather<<<dim3(192, BSZ), 256, 0, stream>>>(tbuf, nnidx, bias, out);
}

// Round 4
// 212.882 us; speedup vs baseline: 1.6571x; 1.6571x over previous
//
#include <hip/hip_runtime.h>
#include <math.h>

#define BSZ 32
#define CCH 192
#define NPIX 784
#define NP 896          // padded N (56 groups of 16)
#define NGRP 56
#define OUTC 384
#define KNN 9
#define CING 96
#define COUTG 96

typedef short s8v __attribute__((ext_vector_type(8)));
typedef float f4v __attribute__((ext_vector_type(4)));

// ---------------- ws layout ----------------
// xf*: [b][g(56)][kc(6)][lane(64)][8] bf16  -> per batch 344 KB
#define XFH_BYTES ((size_t)BSZ * NGRP * 6 * 64 * 8 * 2)   // 11,010,048
#define XFL_BYTES XFH_BYTES
#define SQ_BYTES  ((size_t)BSZ * NP * 4)
#define IDX_BYTES ((size_t)BSZ * NPIX * KNN * 4)
// tbuf: BSZ*192*NPIX*4 = 19,267,584   total ~42.3 MB

__device__ __forceinline__ float gelu_exact(float u) {
    return 0.5f * u * (1.0f + erff(u * 0.70710678118654752440f));
}
__device__ __forceinline__ ushort bf16_rne(float f) {
    uint u = __float_as_uint(f);
    uint r = (u + 0x7fffu + ((u >> 16) & 1u)) >> 16;
    return (ushort)r;
}
__device__ __forceinline__ float bf16f(ushort h) { return __uint_as_float(((uint)h) << 16); }

// ---------------- K1: normalize -> bf16 hi/lo in MFMA-fragment order + sq ----------------
#define HP 200   // LDS row pitch in ushorts (400B: 16B-aligned rows, conflict-light stores)
__global__ __launch_bounds__(256) void k1_normalize(const float* __restrict__ x,
                                                    ushort* __restrict__ xfh,
                                                    ushort* __restrict__ xfl,
                                                    float* __restrict__ sq) {
    __shared__ ushort hs[64 * HP];
    __shared__ ushort ls[64 * HP];
    int b = blockIdx.y;
    int n0 = blockIdx.x * 64;
    int t = threadIdx.x;
    int ln = t >> 2;          // local node 0..63
    int part = t & 3;         // 48 channels each
    int n = n0 + ln;
    const float* xb = x + (size_t)b * CCH * NPIX;

    float ss = 0.f;
    if (n < NPIX) {
        for (int c = part * 48; c < part * 48 + 48; ++c) {
            float v = xb[c * NPIX + n];
            ss = fmaf(v, v, ss);
        }
    }
    ss += __shfl_xor(ss, 1);
    ss += __shfl_xor(ss, 2);
    float inv = 1.0f / fmaxf(sqrtf(ss), 1e-12f);

    float s2 = 0.f;
    for (int c = part * 48; c < part * 48 + 48; ++c) {
        float v = (n < NPIX) ? xb[c * NPIX + n] * inv : 0.f;
        ushort h = bf16_rne(v);
        ushort l = bf16_rne(v - bf16f(h));
        hs[ln * HP + c] = h;
        ls[ln * HP + c] = l;
        s2 = fmaf(v, v, s2);
    }
    s2 += __shfl_xor(s2, 1);
    s2 += __shfl_xor(s2, 2);
    if (part == 0) sq[b * NP + n] = (n < NPIX) ? s2 : 1e30f;

    __syncthreads();
    // write fragment-ordered chunks: 4 groups x 6 kc x 64 lanes, 16B each
    int g0 = n0 >> 4;
#pragma unroll
    for (int i = 0; i < 6; ++i) {
        int ch = t + i * 256;                  // 0..1535
        int g = ch / 384;
        int rem = ch - g * 384;
        int kc = rem >> 6;
        int lane = rem & 63;
        int node = g * 16 + (lane & 15);
        int c0 = kc * 32 + (lane >> 4) * 8;
        size_t doff = (((size_t)(b * NGRP + g0 + g) * 6 + kc) * 64 + lane) * 8;
        *(uint4*)(xfh + doff) = *(const uint4*)&hs[node * HP + c0];
        *(uint4*)(xfl + doff) = *(const uint4*)&ls[node * HP + c0];
    }
}

// ---------------- K2: MFMA knn, fragment-ordered coalesced loads ----------------
__device__ __forceinline__ bool lt_pair(float v, int id, float dv, int di) {
    return (v < dv) || (v == dv && id < di);
}
// strict-< insert: candidate stream per lane is index-ascending, so ties keep
// the earlier (smaller) index -- matches lax.top_k without per-step idx compare
__device__ __forceinline__ void ins9(float (&d)[KNN], int (&ii)[KNN], float v, int id) {
    if (!(v < d[KNN - 1])) return;
    bool cprev = true;
#pragma unroll
    for (int p = KNN - 1; p >= 0; --p) {
        bool cp = (p == 0) ? false : (v < d[p - 1]);
        float nd = cp ? d[p - 1] : (cprev ? v : d[p]);
        int nid = cp ? ii[p - 1] : (cprev ? id : ii[p]);
        d[p] = nd; ii[p] = nid; cprev = cp;
    }
}

__global__ __launch_bounds__(128, 3) void k2_knn(const ushort* __restrict__ xfh,
                                                 const ushort* __restrict__ xfl,
                                                 const float* __restrict__ sq,
                                                 int* __restrict__ nnidx) {
    __shared__ float dls[2][64][KNN];
    __shared__ int   ils[2][64][KNN];
    int wg = blockIdx.x;                       // 1568 = 8 xcd * (4 b * 49 qt)
    int b  = (wg & 7) * 4 + (wg >> 3) / 49;
    int qt = (wg >> 3) % 49;
    int t = threadIdx.x, w = t >> 6, l = t & 63;
    int lk = l >> 4;
    const ushort* fh = xfh + (size_t)b * NGRP * 6 * 512;
    const ushort* fl = xfl + (size_t)b * NGRP * 6 * 512;

    // resident queries: group qt (16 queries), fragment chunk = contiguous 1KB/wave
    s8v qh[6], ql[6];
#pragma unroll
    for (int kc = 0; kc < 6; ++kc) {
        qh[kc] = *(const s8v*)(fh + ((size_t)qt * 6 + kc) * 512 + l * 8);
        ql[kc] = *(const s8v*)(fl + ((size_t)qt * 6 + kc) * 512 + l * 8);
    }

    float d9[KNN]; int i9[KNN];
#pragma unroll
    for (int r = 0; r < KNN; ++r) { d9[r] = 3.4e38f; i9[r] = 0x7fffffff; }

    const float* sqb = sq + b * NP;
    for (int cg0 = 0; cg0 < 28; ++cg0) {
        int cg = w * 28 + cg0;
        const ushort* ch = fh + (size_t)cg * 6 * 512 + l * 8;
        const ushort* cl = fl + (size_t)cg * 6 * 512 + l * 8;
        f4v aH = {0.f, 0.f, 0.f, 0.f};
        f4v aX = {0.f, 0.f, 0.f, 0.f};
#pragma unroll
        for (int kc = 0; kc < 6; ++kc) {
            s8v vh = *(const s8v*)(ch + kc * 512);
            s8v vl = *(const s8v*)(cl + kc * 512);
            aH = __builtin_amdgcn_mfma_f32_16x16x32_bf16(vh, qh[kc], aH, 0, 0, 0);
            aX = __builtin_amdgcn_mfma_f32_16x16x32_bf16(vl, qh[kc], aX, 0, 0, 0);
            aX = __builtin_amdgcn_mfma_f32_16x16x32_bf16(vh, ql[kc], aX, 0, 0, 0);
        }
        f4v sv = *(const f4v*)(sqb + cg * 16 + lk * 4);
#pragma unroll
        for (int r = 0; r < 4; ++r) {
            float dist = fmaf(-2.f, aH[r] + aX[r], sv[r]);
            ins9(d9, i9, dist, cg * 16 + lk * 4 + r);
        }
    }

#pragma unroll
    for (int r = 0; r < KNN; ++r) { dls[w][l][r] = d9[r]; ils[w][l][r] = i9[r]; }
    __syncthreads();
    if (t < 16) {
        int q = qt * 16 + t;
        int pk[8] = {0, 0, 0, 0, 0, 0, 0, 0};
        int* op = nnidx + ((size_t)b * NPIX + q) * KNN;
        for (int r = 0; r < KNN; ++r) {
            float best = 3.4e38f; int bi = 0x7fffffff; int bk = 0;
#pragma unroll
            for (int m = 0; m < 8; ++m) {
                int ww = m >> 2, kk = m & 3;
                int idx = pk[m] < KNN ? pk[m] : KNN - 1;
                float v = dls[ww][kk * 16 + t][idx];
                int ii = ils[ww][kk * 16 + t][idx];
                if (pk[m] < KNN && lt_pair(v, ii, best, bi)) { best = v; bi = ii; bk = m; }
            }
            op[r] = bi;
#pragma unroll
            for (int m = 0; m < 8; ++m) pk[m] += (m == bk) ? 1 : 0;
        }
    }
}

// ---------------- K3: t[og,n] = dot96(w[og], x[half,:,n]); fused gelu for groups 0/1 ----------------
#define NT3 128
__global__ __launch_bounds__(256) void k3_proj(const float* __restrict__ x,
                                               const float* __restrict__ w,
                                               const float* __restrict__ bias,
                                               float* __restrict__ out,
                                               float* __restrict__ tbuf) {
    __shared__ float wgT[CING][COUTG + 1];   // [c][og]
    __shared__ float xc[16][NT3];
    int nt = blockIdx.x;     // 0..6
    int g  = blockIdx.y;     // 0..3
    int b  = blockIdx.z;
    int t  = threadIdx.x;
    int n0 = nt * NT3;
    int tog = t >> 4;        // 0..15 : og = tog*6 .. +5
    int tn  = t & 15;        // n = n0 + tn*8 .. +7

    for (int i = t; i < CING * COUTG; i += 256) {
        int og = i / 96, c = i - og * 96;
        wgT[c][og] = w[(g * COUTG + og) * CING + c];
    }

    float acc[6][8];
#pragma unroll
    for (int i = 0; i < 6; ++i)
#pragma unroll
        for (int j = 0; j < 8; ++j) acc[i][j] = 0.f;

    int chalf = (g & 1) * CING;
    for (int cc = 0; cc < CING; cc += 16) {
        __syncthreads();
#pragma unroll
        for (int i = t; i < 16 * NT3; i += 256) {
            int ci = i >> 7, ni = i & 127;
            int gn = n0 + ni;
            xc[ci][ni] = (gn < NPIX) ? x[((size_t)b * CCH + chalf + cc + ci) * NPIX + gn] : 0.f;
        }
        __syncthreads();
#pragma unroll
        for (int ci = 0; ci < 16; ++ci) {
            float wv[6];
#pragma unroll
            for (int i = 0; i < 6; ++i) wv[i] = wgT[cc + ci][tog * 6 + i];
            const float4 xa = *(const float4*)&xc[ci][tn * 8];
            const float4 xb2 = *(const float4*)&xc[ci][tn * 8 + 4];
            float xv[8] = {xa.x, xa.y, xa.z, xa.w, xb2.x, xb2.y, xb2.z, xb2.w};
#pragma unroll
            for (int i = 0; i < 6; ++i)
#pragma unroll
                for (int j = 0; j < 8; ++j)
                    acc[i][j] = fmaf(wv[i], xv[j], acc[i][j]);
        }
    }

#pragma unroll
    for (int i = 0; i < 6; ++i) {
        int og = tog * 6 + i;
        int ogg = g * COUTG + og;
        float bv = bias[ogg];
#pragma unroll
        for (int j = 0; j < 8; ++j) {
            int n = n0 + tn * 8 + j;
            if (n < NPIX) {
                if (g < 2)
                    out[((size_t)b * OUTC + ogg) * NPIX + n] = gelu_exact(acc[i][j] + bv);
                else
                    tbuf[((size_t)b * 192 + (g - 2) * COUTG + og) * NPIX + n] = acc[i][j];
            }
        }
    }
}

// ---------------- K4: groups 2/3  out = max_k gelu(t[idx_k] - t[n] + bias) ----------------
// gelu is unimodal (min at u*~-0.752): max over set = max(gelu(umin), gelu(umax))
__global__ __launch_bounds__(256) void k4_gather(const float* __restrict__ tbuf,
                                                 const int* __restrict__ nnidx,
                                                 const float* __restrict__ bias,
                                                 float* __restrict__ out) {
    __shared__ float trow[NPIX];
    int og2 = blockIdx.x;    // 0..191
    int b = blockIdx.y;
    int t = threadIdx.x;
    const float* tr = tbuf + ((size_t)b * 192 + og2) * NPIX;
    for (int i = t; i < NPIX; i += 256) trow[i] = tr[i];
    __syncthreads();
    float bv = bias[192 + og2];
    for (int n = t; n < NPIX; n += 256) {
        float ti = trow[n];
        const int* ip = nnidx + ((size_t)b * NPIX + n) * KNN;
        float umin = 3.4e38f, umax = -3.4e38f;
#pragma unroll
        for (int k = 0; k < KNN; ++k) {
            int j = ip[k];
            float u = trow[j] - ti + bv;
            umin = fminf(umin, u);
            umax = fmaxf(umax, u);
        }
        float m = fmaxf(gelu_exact(umin), gelu_exact(umax));
        out[((size_t)b * OUTC + 192 + og2) * NPIX + n] = m;
    }
}

extern "C" void kernel_launch(void* const* d_in, const int* in_sizes, int n_in,
                              void* d_out, int out_size, void* d_ws, size_t ws_size,
                              hipStream_t stream) {
    const float* x    = (const float*)d_in[0];
    const float* w    = (const float*)d_in[1];
    const float* bias = (const float*)d_in[2];
    float* out = (float*)d_out;
    char* ws = (char*)d_ws;

    ushort* xfh  = (ushort*)(ws);
    ushort* xfl  = (ushort*)(ws + XFH_BYTES);
    float*  sq   = (float*) (ws + XFH_BYTES + XFL_BYTES);
    int*    nnidx= (int*)   (ws + XFH_BYTES + XFL_BYTES + SQ_BYTES);
    float*  tbuf = (float*) (ws + XFH_BYTES + XFL_BYTES + SQ_BYTES + IDX_BYTES);

    k1_normalize<<<dim3(NP / 64, BSZ), 256, 0, stream>>>(x, xfh, xfl, sq);
    k2_knn<<<dim3(1568), 128, 0, stream>>>(xfh, xfl, sq, nnidx);
    k3_proj<<<dim3(7, 4, BSZ), 256, 0, stream>>>(x, w, bias, out, tbuf);
    k4_gather<<<dim3(192, BSZ), 256, 0, stream>>>(tbuf, nnidx, bias, out);
}